// Round 9
// baseline (294.838 us; speedup 1.0000x reference)
//
#include <hip/hip_runtime.h>

#define NN 50000
#define NNP 50016   // 1563 * 32, padded rows for the GEMM
#define NE 800000
#define DIN 64
#define HD 128
#define NBUK 196            // ceil(NN/256) coarse buckets (dst>>8)
#define SB 196              // ceil(NE/4096) scatter chunks
#define BCAP 12288          // build_csr LDS capacity (edges per bucket fast path)
#define NCHUNK 3125         // ceil(NN/16) node chunks for sliced gathers

typedef __attribute__((ext_vector_type(8))) short short8;
typedef __attribute__((ext_vector_type(4))) float f32x4;
typedef __attribute__((ext_vector_type(4))) unsigned short us4;
typedef __attribute__((ext_vector_type(8))) unsigned short us8;

__device__ __forceinline__ unsigned short f2bf(float f) {
    unsigned int u = __float_as_uint(f);
    u = (u + 0x7FFFu + ((u >> 16) & 1u)) >> 16;
    return (unsigned short)u;
}
__device__ __forceinline__ float bf2f(unsigned short u) {
    return __uint_as_float(((unsigned int)u) << 16);
}

// inclusive Hillis-Steele scan over a[256]; all 256 threads must execute
#define LDS_SCAN256(a, t)                                 \
    for (int off_ = 1; off_ < 256; off_ <<= 1) {          \
        int add_ = ((t) >= off_) ? (a)[(t) - off_] : 0;   \
        __syncthreads();                                  \
        (a)[t] += add_;                                   \
        __syncthreads();                                  \
    }

// ---------------- CSR via two-level LDS counting sort ----------------

__global__ void zero_meta(int* __restrict__ meta) {
    meta[threadIdx.x] = 0;  // 512 threads: bcnt[256] + bfill[256]
}

__global__ __launch_bounds__(256) void bucket_count(const int* __restrict__ dst,
                                                    int* __restrict__ bcnt) {
    __shared__ int lc[256];
    int t = threadIdx.x;
    lc[t] = 0;
    __syncthreads();
    int base = blockIdx.x * 4096 + t * 16;
#pragma unroll
    for (int j = 0; j < 4; ++j) {
        int e = base + j * 4;
        if (e < NE) {
            int4 d = *(const int4*)(dst + e);
            atomicAdd(&lc[d.x >> 8], 1);
            atomicAdd(&lc[d.y >> 8], 1);
            atomicAdd(&lc[d.z >> 8], 1);
            atomicAdd(&lc[d.w >> 8], 1);
        }
    }
    __syncthreads();
    if (t < NBUK && lc[t] > 0) atomicAdd(&bcnt[t], lc[t]);
}

__global__ __launch_bounds__(256) void bucket_scan(const int* __restrict__ bcnt,
                                                   int* __restrict__ bbase,
                                                   int* __restrict__ rowptr) {
    __shared__ int sh[256];
    int t = threadIdx.x;
    int v = (t < NBUK) ? bcnt[t] : 0;
    sh[t] = v;
    __syncthreads();
    LDS_SCAN256(sh, t);
    if (t < NBUK) bbase[t] = sh[t] - v;   // exclusive
    if (t == NBUK - 1) bbase[NBUK] = sh[t];
    if (t == 0) rowptr[NN] = NE;
}

__global__ __launch_bounds__(256) void bucket_scatter(
    const int* __restrict__ src, const int* __restrict__ dst,
    const int* __restrict__ bbase, int* __restrict__ bfill,
    int2* __restrict__ pairs) {
    __shared__ int cnt[256];
    __shared__ int incl[256];
    __shared__ int lfill[256];
    __shared__ int rung[256];
    __shared__ int2 buf[4096];
    int t = threadIdx.x;
    cnt[t] = 0;
    lfill[t] = 0;
    __syncthreads();
    int base = blockIdx.x * 4096 + t * 16;
    // phase A: local bucket histogram
#pragma unroll
    for (int j = 0; j < 4; ++j) {
        int e = base + j * 4;
        if (e < NE) {
            int4 d = *(const int4*)(dst + e);
            atomicAdd(&cnt[d.x >> 8], 1);
            atomicAdd(&cnt[d.y >> 8], 1);
            atomicAdd(&cnt[d.z >> 8], 1);
            atomicAdd(&cnt[d.w >> 8], 1);
        }
    }
    __syncthreads();
    incl[t] = cnt[t];
    __syncthreads();
    LDS_SCAN256(incl, t);
    // phase B: allocate one global run per non-empty bucket
    int c = cnt[t];
    if (t < NBUK && c > 0) rung[t] = bbase[t] + atomicAdd(&bfill[t], c);
    __syncthreads();
    // phase C: local scatter into LDS, grouped by bucket
#pragma unroll
    for (int j = 0; j < 4; ++j) {
        int e = base + j * 4;
        if (e < NE) {
            int4 s4 = *(const int4*)(src + e);
            int4 d4 = *(const int4*)(dst + e);
            int ss[4] = {s4.x, s4.y, s4.z, s4.w};
            int dd[4] = {d4.x, d4.y, d4.z, d4.w};
#pragma unroll
            for (int q = 0; q < 4; ++q) {
                int k = dd[q] >> 8;
                int p = (incl[k] - cnt[k]) + atomicAdd(&lfill[k], 1);
                buf[p] = {ss[q], dd[q]};
            }
        }
    }
    __syncthreads();
    // phase D: coalesced run writes
    int n = min(4096, NE - blockIdx.x * 4096);
    for (int i = t; i < n; i += 256) {
        int2 pr = buf[i];
        int k = pr.y >> 8;
        pairs[rung[k] + (i - (incl[k] - cnt[k]))] = pr;
    }
}

__global__ __launch_bounds__(256) void build_csr(
    const int2* __restrict__ pairs, const int* __restrict__ bbase,
    int* __restrict__ rowptr, float* __restrict__ invcnt,
    int* __restrict__ csr_src) {
    __shared__ int cnt[256];
    __shared__ int incl[256];
    __shared__ int lfill[256];
    __shared__ int sbuf[BCAP];
    int b = blockIdx.x, t = threadIdx.x;
    int pbeg = bbase[b], pend = bbase[b + 1];
    int sz = pend - pbeg;
    cnt[t] = 0;
    lfill[t] = 0;
    __syncthreads();
    for (int i = t; i < sz; i += 256)
        atomicAdd(&cnt[pairs[pbeg + i].y & 255], 1);
    __syncthreads();
    incl[t] = cnt[t];
    __syncthreads();
    LDS_SCAN256(incl, t);
    int node = b * 256 + t;
    int c = cnt[t];
    if (node < NN) {
        rowptr[node] = pbeg + incl[t] - c;   // global exclusive position
        invcnt[node] = 1.0f / (float)(c > 0 ? c : 1);
    }
    if (sz <= BCAP) {
        for (int i = t; i < sz; i += 256) {
            int2 pr = pairs[pbeg + i];
            int ld = pr.y & 255;
            sbuf[(incl[ld] - cnt[ld]) + atomicAdd(&lfill[ld], 1)] = pr.x;
        }
        __syncthreads();
        for (int i = t; i < sz; i += 256) csr_src[pbeg + i] = sbuf[i];
    } else {  // safety fallback (not hit for uniform dst)
        for (int i = t; i < sz; i += 256) {
            int2 pr = pairs[pbeg + i];
            int ld = pr.y & 255;
            csr_src[pbeg + (incl[ld] - cnt[ld]) + atomicAdd(&lfill[ld], 1)] = pr.x;
        }
    }
}

// ---------------- prep: pack weights into MFMA B-fragment order (bf16) ----------------

__device__ __forceinline__ void pack_one(const float* Wl, const float* Wr, int D,
                                         unsigned short* Wpk, int i) {
    int j = i & 7;
    int lane = (i >> 3) & 63;
    int ct = (i >> 9) & 7;
    int ks = i >> 12;
    int k = ks * 32 + ((lane >> 4) << 3) + j;
    int c = ct * 16 + (lane & 15);
    float v = (k < D) ? Wl[c * D + k] : Wr[c * D + (k - D)];
    Wpk[i] = f2bf(v);
}

__global__ void pack_weights(const float* __restrict__ Wl0, const float* __restrict__ Wr0,
                             const float* __restrict__ Wl1, const float* __restrict__ Wr1,
                             const float* __restrict__ Wl2, const float* __restrict__ Wr2,
                             unsigned short* __restrict__ Wpk0,
                             unsigned short* __restrict__ Wpk1,
                             unsigned short* __restrict__ Wpk2) {
    const int S0 = 2 * DIN * HD;   // 16384
    const int S12 = 2 * HD * HD;   // 32768
    int i = blockIdx.x * blockDim.x + threadIdx.x;
    if (i < S0) { pack_one(Wl0, Wr0, DIN, Wpk0, i); return; }
    int j = i - S0;
    if (j < S12) { pack_one(Wl1, Wr1, HD, Wpk1, j); return; }
    int m = j - S12;
    if (m < S12) pack_one(Wl2, Wr2, HD, Wpk2, m);
}

// x f32 [NN][64] -> bf16 into A0[:, 64:128] (row stride 128 shorts; h-half = one 128B line)
__global__ void conv_x(const float* __restrict__ x, unsigned short* __restrict__ A0) {
    int i = blockIdx.x * blockDim.x + threadIdx.x;  // NN*16 chunks
    if (i >= NN * 16) return;
    int row = i >> 4, c4 = i & 15;
    float4 v = ((const float4*)(x + (size_t)row * DIN))[c4];
    us4 o = {f2bf(v.x), f2bf(v.y), f2bf(v.z), f2bf(v.w)};
    *(us4*)(A0 + (size_t)row * 128 + 64 + c4 * 4) = o;
}

// ---------------- gather-mean layer 0: XCD channel-sliced, shuffle reduce ----------------
// slice s = blockIdx & 7 (-> XCD s via round-robin dispatch): 8 channels = 16B per edge.
// block: 4 waves x 4 nodes x 16 lanes; lane16 = edge-group (16 groups x us8).

__global__ __launch_bounds__(256) void gather_mean_x(
    const int* __restrict__ rowptr, const int* __restrict__ csr_src,
    const float* __restrict__ invcnt, unsigned short* __restrict__ A0) {
    int s = blockIdx.x & 7;
    int chunk = blockIdx.x >> 3;
    int tid = threadIdx.x;
    int n = chunk * 16 + (tid >> 4);
    if (n >= NN) return;
    int eg = tid & 15;
    int beg = rowptr[n], end = rowptr[n + 1];
    float acc[8] = {};
    const unsigned short* hb = A0 + 64 + (size_t)s * 8;
    for (int e = beg + eg; e < end; e += 16) {
        us8 v = *(const us8*)(hb + (size_t)csr_src[e] * 128);
#pragma unroll
        for (int j = 0; j < 8; ++j) acc[j] += bf2f(v[j]);
    }
#pragma unroll
    for (int j = 0; j < 8; ++j) {
        acc[j] += __shfl_xor(acc[j], 1, 64);
        acc[j] += __shfl_xor(acc[j], 2, 64);
        acc[j] += __shfl_xor(acc[j], 4, 64);
        acc[j] += __shfl_xor(acc[j], 8, 64);
    }
    if (eg == 0) {
        float ic = invcnt[n];
        us8 o;
#pragma unroll
        for (int j = 0; j < 8; ++j) o[j] = f2bf(acc[j] * ic);
        *(us8*)(A0 + (size_t)n * 128 + s * 8) = o;
    }
}

// ---------------- gather-mean layers 1,2: XCD channel-sliced, shuffle reduce ----------------
// slice s = blockIdx & 7: 16 channels = 32B per edge (2 ch-lanes x us8).
// block: 4 waves x 4 nodes x 16 lanes; lane16 = eg*2 + cl (8 edge-groups x 2 ch-lanes).

__global__ __launch_bounds__(256) void gather_mean_h(
    const unsigned short* __restrict__ A12, const int* __restrict__ rowptr,
    const int* __restrict__ csr_src, const float* __restrict__ invcnt,
    unsigned short* __restrict__ Am) {
    int s = blockIdx.x & 7;
    int chunk = blockIdx.x >> 3;
    int tid = threadIdx.x;
    int n = chunk * 16 + (tid >> 4);
    if (n >= NN) return;
    int l16 = tid & 15;
    int eg = l16 >> 1, cl = l16 & 1;
    int beg = rowptr[n], end = rowptr[n + 1];
    float acc[8] = {};
    const unsigned short* hb = A12 + 128 + (size_t)s * 16 + (size_t)cl * 8;
    for (int e = beg + eg; e < end; e += 8) {
        us8 v = *(const us8*)(hb + (size_t)csr_src[e] * 256);
#pragma unroll
        for (int j = 0; j < 8; ++j) acc[j] += bf2f(v[j]);
    }
#pragma unroll
    for (int j = 0; j < 8; ++j) {
        acc[j] += __shfl_xor(acc[j], 2, 64);
        acc[j] += __shfl_xor(acc[j], 4, 64);
        acc[j] += __shfl_xor(acc[j], 8, 64);
    }
    if (eg == 0) {
        float ic = invcnt[n];
        us8 o;
#pragma unroll
        for (int j = 0; j < 8; ++j) o[j] = f2bf(acc[j] * ic);
        *(us8*)(Am + (size_t)n * 256 + s * 16 + cl * 8) = o;
    }
}

// ---------------- fused MFMA GEMM + bias + L2 norm + (ReLU) ----------------

template <int K, bool RELU, bool F32OUT, bool BF16H>
__global__ __launch_bounds__(256) void linear_mfma(
    const unsigned short* __restrict__ A, const unsigned short* __restrict__ Wpk,
    const float* __restrict__ bias, float* __restrict__ outF,
    unsigned short* __restrict__ Hn /* h-part base (stride 256) */) {
    constexpr int NK = K / 32;
    __shared__ float rsum[2][32];
    int tid = threadIdx.x;
    int lane = tid & 63, w = tid >> 6;
    int rg = w >> 1, cg = w & 1;
    int r0 = blockIdx.x * 32 + rg * 16;
    int row_l = lane & 15, kb = lane >> 4;

    const unsigned short* Arow = A + (size_t)(r0 + row_l) * K + kb * 8;
    const unsigned short* Wp = Wpk + ((size_t)(cg * 4) * 64 + lane) * 8;

    f32x4 acc[4] = {{0.f, 0.f, 0.f, 0.f}, {0.f, 0.f, 0.f, 0.f},
                    {0.f, 0.f, 0.f, 0.f}, {0.f, 0.f, 0.f, 0.f}};
#pragma unroll
    for (int ks = 0; ks < NK; ++ks) {
        short8 a = *(const short8*)(Arow + ks * 32);
#pragma unroll
        for (int t = 0; t < 4; ++t) {
            short8 b = *(const short8*)(Wp + ((size_t)ks * 8 + t) * 64 * 8);
            acc[t] = __builtin_amdgcn_mfma_f32_16x16x32_bf16(a, b, acc[t], 0, 0, 0);
        }
    }

    float sq[4] = {0.f, 0.f, 0.f, 0.f};
#pragma unroll
    for (int t = 0; t < 4; ++t) {
        float bv = bias[cg * 64 + t * 16 + row_l];
#pragma unroll
        for (int r = 0; r < 4; ++r) {
            acc[t][r] += bv;
            sq[r] = fmaf(acc[t][r], acc[t][r], sq[r]);
        }
    }
#pragma unroll
    for (int off = 1; off < 16; off <<= 1)
#pragma unroll
        for (int r = 0; r < 4; ++r) sq[r] += __shfl_xor(sq[r], off, 64);

    if (row_l == 0) {
#pragma unroll
        for (int r = 0; r < 4; ++r) rsum[cg][rg * 16 + kb * 4 + r] = sq[r];
    }
    __syncthreads();  // also orders all A reads before the BF16H in-place writes

    int rbase = rg * 16 + kb * 4;
#pragma unroll
    for (int r = 0; r < 4; ++r) {
        int row = r0 + kb * 4 + r;
        if (row >= NN) continue;
        float n2 = rsum[0][rbase + r] + rsum[1][rbase + r];
        float inv = 1.0f / fmaxf(sqrtf(n2), 1e-12f);
#pragma unroll
        for (int t = 0; t < 4; ++t) {
            float v = acc[t][r] * inv;
            if (RELU) v = fmaxf(v, 0.f);
            int c = cg * 64 + t * 16 + row_l;
            if (F32OUT) outF[(size_t)row * HD + c] = v;
            if (BF16H) Hn[(size_t)row * 256 + c] = f2bf(v);
        }
    }
}

// ---------------- launch ----------------

static inline size_t align256(size_t x) { return (x + 255) & ~(size_t)255; }

extern "C" void kernel_launch(void* const* d_in, const int* in_sizes, int n_in,
                              void* d_out, int out_size, void* d_ws, size_t ws_size,
                              hipStream_t stream) {
    const float* x   = (const float*)d_in[0];
    const int*   ei  = (const int*)d_in[1];
    const float* Wl0 = (const float*)d_in[2];
    const float* bl0 = (const float*)d_in[3];
    const float* Wr0 = (const float*)d_in[4];
    const float* Wl1 = (const float*)d_in[5];
    const float* bl1 = (const float*)d_in[6];
    const float* Wr1 = (const float*)d_in[7];
    const float* Wl2 = (const float*)d_in[8];
    const float* bl2 = (const float*)d_in[9];
    const float* Wr2 = (const float*)d_in[10];

    const int* src = ei;
    const int* dst = ei + NE;

    // workspace carve-up
    char* p = (char*)d_ws;
    size_t off = 0;
    int* meta = (int*)(p + off);            off = align256(off + 512 * 4);  // bcnt[256]+bfill[256]
    int* bbase = (int*)(p + off);           off = align256(off + 256 * 4);
    int* rowptr = (int*)(p + off);          off = align256(off + (size_t)(NN + 1) * 4);
    int* csr_src = (int*)(p + off);         off = align256(off + (size_t)NE * 4);
    float* invcnt = (float*)(p + off);      off = align256(off + (size_t)NN * 4);
    int2* pairs = (int2*)(p + off);         off = align256(off + (size_t)NE * 8);
    unsigned short* A0 = (unsigned short*)(p + off);   off = align256(off + (size_t)NNP * 128 * 2);
    unsigned short* A12 = (unsigned short*)(p + off);  off = align256(off + (size_t)NNP * 256 * 2);
    unsigned short* Wpk0 = (unsigned short*)(p + off); off = align256(off + (size_t)2 * DIN * HD * 2);
    unsigned short* Wpk1 = (unsigned short*)(p + off); off = align256(off + (size_t)2 * HD * HD * 2);
    unsigned short* Wpk2 = (unsigned short*)(p + off); off = align256(off + (size_t)2 * HD * HD * 2);
    (void)ws_size; (void)n_in; (void)in_sizes; (void)out_size;

    int* bcnt = meta;
    int* bfill = meta + 256;
    float* out = (float*)d_out;

    // CSR build: two-level LDS counting sort (coalesced writes, no cross-XCD line sharing)
    zero_meta<<<1, 512, 0, stream>>>(meta);
    bucket_count<<<SB, 256, 0, stream>>>(dst, bcnt);
    bucket_scan<<<1, 256, 0, stream>>>(bcnt, bbase, rowptr);
    bucket_scatter<<<SB, 256, 0, stream>>>(src, dst, bbase, bfill, pairs);
    build_csr<<<NBUK, 256, 0, stream>>>(pairs, bbase, rowptr, invcnt, csr_src);

    // prep (independent of CSR): packed weights + dense x->bf16 into A0 h-half
    const int WTOT = 2 * DIN * HD + 2 * 2 * HD * HD;  // 81920
    pack_weights<<<(WTOT + 255) / 256, 256, 0, stream>>>(Wl0, Wr0, Wl1, Wr1, Wl2, Wr2,
                                                         Wpk0, Wpk1, Wpk2);
    conv_x<<<(NN * 16 + 255) / 256, 256, 0, stream>>>(x, A0);

    const int LG = NNP / 32;        // 1563
    const int GG = 8 * NCHUNK;      // 25000 sliced gather blocks (slice = blockIdx & 7)

    // layer 0: gather bf16 x rows (sliced) -> A0 mean part; GEMM K=128 -> h0 into A12[:,128:256]
    gather_mean_x<<<GG, 256, 0, stream>>>(rowptr, csr_src, invcnt, A0);
    linear_mfma<2 * DIN, true, false, true><<<LG, 256, 0, stream>>>(
        A0, Wpk0, bl0, nullptr, A12 + 128);

    // layer 1: gather h0 (sliced) -> A12 mean part; GEMM K=256 -> h1 bf16 (in place)
    gather_mean_h<<<GG, 256, 0, stream>>>(A12, rowptr, csr_src, invcnt, A12);
    linear_mfma<2 * HD, true, false, true><<<LG, 256, 0, stream>>>(
        A12, Wpk1, bl1, nullptr, A12 + 128);

    // layer 2: gather h1 (sliced) -> A12 mean part; GEMM K=256 -> f32 d_out
    gather_mean_h<<<GG, 256, 0, stream>>>(A12, rowptr, csr_src, invcnt, A12);
    linear_mfma<2 * HD, false, true, false><<<LG, 256, 0, stream>>>(
        A12, Wpk2, bl2, out, nullptr);
}

// Round 11
// 199.022 us; speedup vs baseline: 1.4814x; 1.4814x over previous
//
#include <hip/hip_runtime.h>

#define NN 50000
#define NNP 50016   // 1563 * 32, padded rows for the GEMM
#define NE 800000
#define DIN 64
#define HD 128
#define NBUK 196            // ceil(NN/256) coarse buckets (dst>>8)
#define SB 196              // ceil(NE/4096) scatter chunks
#define BCAP 12288          // build_csr LDS capacity (edges per bucket fast path)
#define NCHUNK 3125         // NN/16 node chunks for sliced gathers

typedef __attribute__((ext_vector_type(8))) short short8;
typedef __attribute__((ext_vector_type(4))) float f32x4;
typedef __attribute__((ext_vector_type(4))) unsigned short us4;
typedef __attribute__((ext_vector_type(8))) unsigned short us8;

__device__ __forceinline__ unsigned short f2bf(float f) {
    unsigned int u = __float_as_uint(f);
    u = (u + 0x7FFFu + ((u >> 16) & 1u)) >> 16;
    return (unsigned short)u;
}
__device__ __forceinline__ float bf2f(unsigned short u) {
    return __uint_as_float(((unsigned int)u) << 16);
}

// inclusive Hillis-Steele scan over a[256]; all 256 threads must execute
#define LDS_SCAN256(a, t)                                 \
    for (int off_ = 1; off_ < 256; off_ <<= 1) {          \
        int add_ = ((t) >= off_) ? (a)[(t) - off_] : 0;   \
        __syncthreads();                                  \
        (a)[t] += add_;                                   \
        __syncthreads();                                  \
    }

// ---------------- CSR via two-level LDS counting sort ----------------

__global__ __launch_bounds__(256) void bucket_count(const int* __restrict__ dst,
                                                    int* __restrict__ bcnt) {
    __shared__ int lc[256];
    int t = threadIdx.x;
    lc[t] = 0;
    __syncthreads();
    int base = blockIdx.x * 4096 + t * 16;
#pragma unroll
    for (int j = 0; j < 4; ++j) {
        int e = base + j * 4;
        if (e < NE) {
            int4 d = *(const int4*)(dst + e);
            atomicAdd(&lc[d.x >> 8], 1);
            atomicAdd(&lc[d.y >> 8], 1);
            atomicAdd(&lc[d.z >> 8], 1);
            atomicAdd(&lc[d.w >> 8], 1);
        }
    }
    __syncthreads();
    if (t < NBUK && lc[t] > 0) atomicAdd(&bcnt[t], lc[t]);
}

__global__ __launch_bounds__(256) void bucket_scan(const int* __restrict__ bcnt,
                                                   int* __restrict__ bbase,
                                                   int* __restrict__ rowptr) {
    __shared__ int sh[256];
    int t = threadIdx.x;
    int v = (t < NBUK) ? bcnt[t] : 0;
    sh[t] = v;
    __syncthreads();
    LDS_SCAN256(sh, t);
    if (t < NBUK) bbase[t] = sh[t] - v;   // exclusive
    if (t == NBUK - 1) bbase[NBUK] = sh[t];
    if (t == 0) rowptr[NN] = NE;
}

__global__ __launch_bounds__(256) void bucket_scatter(
    const int* __restrict__ src, const int* __restrict__ dst,
    const int* __restrict__ bbase, int* __restrict__ bfill,
    int2* __restrict__ pairs) {
    __shared__ int cnt[256];
    __shared__ int incl[256];
    __shared__ int lfill[256];
    __shared__ int rung[256];
    __shared__ int2 buf[4096];
    int t = threadIdx.x;
    cnt[t] = 0;
    lfill[t] = 0;
    __syncthreads();
    int base = blockIdx.x * 4096 + t * 16;
#pragma unroll
    for (int j = 0; j < 4; ++j) {
        int e = base + j * 4;
        if (e < NE) {
            int4 d = *(const int4*)(dst + e);
            atomicAdd(&cnt[d.x >> 8], 1);
            atomicAdd(&cnt[d.y >> 8], 1);
            atomicAdd(&cnt[d.z >> 8], 1);
            atomicAdd(&cnt[d.w >> 8], 1);
        }
    }
    __syncthreads();
    incl[t] = cnt[t];
    __syncthreads();
    LDS_SCAN256(incl, t);
    int c = cnt[t];
    if (t < NBUK && c > 0) rung[t] = bbase[t] + atomicAdd(&bfill[t], c);
    __syncthreads();
#pragma unroll
    for (int j = 0; j < 4; ++j) {
        int e = base + j * 4;
        if (e < NE) {
            int4 s4 = *(const int4*)(src + e);
            int4 d4 = *(const int4*)(dst + e);
            int ss[4] = {s4.x, s4.y, s4.z, s4.w};
            int dd[4] = {d4.x, d4.y, d4.z, d4.w};
#pragma unroll
            for (int q = 0; q < 4; ++q) {
                int k = dd[q] >> 8;
                int p = (incl[k] - cnt[k]) + atomicAdd(&lfill[k], 1);
                buf[p] = {ss[q], dd[q]};
            }
        }
    }
    __syncthreads();
    int n = min(4096, NE - blockIdx.x * 4096);
    for (int i = t; i < n; i += 256) {
        int2 pr = buf[i];
        int k = pr.y >> 8;
        pairs[rung[k] + (i - (incl[k] - cnt[k]))] = pr;
    }
}

__global__ __launch_bounds__(256) void build_csr(
    const int2* __restrict__ pairs, const int* __restrict__ bbase,
    int* __restrict__ rowptr, float* __restrict__ invcnt,
    int* __restrict__ csr_src) {
    __shared__ int cnt[256];
    __shared__ int incl[256];
    __shared__ int lfill[256];
    __shared__ int sbuf[BCAP];
    int b = blockIdx.x, t = threadIdx.x;
    int pbeg = bbase[b], pend = bbase[b + 1];
    int sz = pend - pbeg;
    cnt[t] = 0;
    lfill[t] = 0;
    __syncthreads();
    for (int i = t; i < sz; i += 256)
        atomicAdd(&cnt[pairs[pbeg + i].y & 255], 1);
    __syncthreads();
    incl[t] = cnt[t];
    __syncthreads();
    LDS_SCAN256(incl, t);
    int node = b * 256 + t;
    int c = cnt[t];
    if (node < NN) {
        rowptr[node] = pbeg + incl[t] - c;
        invcnt[node] = 1.0f / (float)(c > 0 ? c : 1);
    }
    if (sz <= BCAP) {
        for (int i = t; i < sz; i += 256) {
            int2 pr = pairs[pbeg + i];
            int ld = pr.y & 255;
            sbuf[(incl[ld] - cnt[ld]) + atomicAdd(&lfill[ld], 1)] = pr.x;
        }
        __syncthreads();
        for (int i = t; i < sz; i += 256) csr_src[pbeg + i] = sbuf[i];
    } else {
        for (int i = t; i < sz; i += 256) {
            int2 pr = pairs[pbeg + i];
            int ld = pr.y & 255;
            csr_src[pbeg + (incl[ld] - cnt[ld]) + atomicAdd(&lfill[ld], 1)] = pr.x;
        }
    }
}

// ---------------- prep: zero meta + pack weights + x -> bf16 sliced ----------------

__device__ __forceinline__ void pack_one(const float* Wl, const float* Wr, int D,
                                         unsigned short* Wpk, int i) {
    int j = i & 7;
    int lane = (i >> 3) & 63;
    int ct = (i >> 9) & 7;
    int ks = i >> 12;
    int k = ks * 32 + ((lane >> 4) << 3) + j;
    int c = ct * 16 + (lane & 15);
    float v = (k < D) ? Wl[c * D + k] : Wr[c * D + (k - D)];
    Wpk[i] = f2bf(v);
}

#define PACK_BLOCKS 320   // 81920/256
#define CONV_BLOCKS 3125  // NN*16/256

__global__ __launch_bounds__(256) void prep(
    const float* __restrict__ Wl0, const float* __restrict__ Wr0,
    const float* __restrict__ Wl1, const float* __restrict__ Wr1,
    const float* __restrict__ Wl2, const float* __restrict__ Wr2,
    unsigned short* __restrict__ Wpk0, unsigned short* __restrict__ Wpk1,
    unsigned short* __restrict__ Wpk2,
    const float* __restrict__ x, unsigned short* __restrict__ Xs,
    int* __restrict__ meta) {
    const int S0 = 2 * DIN * HD;   // 16384
    const int S12 = 2 * HD * HD;   // 32768
    int b = blockIdx.x;
    int t = threadIdx.x;
    if (b < PACK_BLOCKS) {
        int i = b * 256 + t;
        if (i < S0) { pack_one(Wl0, Wr0, DIN, Wpk0, i); return; }
        int j = i - S0;
        if (j < S12) { pack_one(Wl1, Wr1, HD, Wpk1, j); return; }
        int m = j - S12;
        if (m < S12) pack_one(Wl2, Wr2, HD, Wpk2, m);
        return;
    }
    if (b < PACK_BLOCKS + CONV_BLOCKS) {
        // x f32 [NN][64] -> bf16 slice-major Xs[8][NNP][8]
        int i = (b - PACK_BLOCKS) * 256 + t;   // < NN*16
        int row = i >> 4, c4 = i & 15;
        float4 v = ((const float4*)(x + (size_t)row * DIN))[c4];
        us4 o = {f2bf(v.x), f2bf(v.y), f2bf(v.z), f2bf(v.w)};
        *(us4*)(Xs + (size_t)(c4 >> 1) * NNP * 8 + (size_t)row * 8 + (c4 & 1) * 4) = o;
        return;
    }
    // last block: zero meta (bcnt[256] + bfill[256]) — 256 threads cover 512 ints
    meta[t] = 0;
    meta[t + 256] = 0;
}

// ---------------- gather-mean layer 0: slice-major, XCD-pinned, shuffle reduce ----------------
// slice s = blockIdx&7 (-> XCD s); Xs[s] = [NNP][8] bf16. 16 nodes/block, 16 edge-groups/node.

__global__ __launch_bounds__(256) void gather_mean_x(
    const int* __restrict__ rowptr, const int* __restrict__ csr_src,
    const float* __restrict__ invcnt, const unsigned short* __restrict__ Xs,
    unsigned short* __restrict__ M0s) {
    int s = blockIdx.x & 7;
    int chunk = blockIdx.x >> 3;
    int tid = threadIdx.x;
    int n = chunk * 16 + (tid >> 4);
    int eg = tid & 15;
    int beg = rowptr[n], end = rowptr[n + 1];
    float acc[8] = {};
    const unsigned short* hb = Xs + (size_t)s * NNP * 8;
    for (int e = beg + eg; e < end; e += 16) {
        us8 v = *(const us8*)(hb + (size_t)csr_src[e] * 8);
#pragma unroll
        for (int j = 0; j < 8; ++j) acc[j] += bf2f(v[j]);
    }
#pragma unroll
    for (int j = 0; j < 8; ++j) {
        acc[j] += __shfl_xor(acc[j], 1, 64);
        acc[j] += __shfl_xor(acc[j], 2, 64);
        acc[j] += __shfl_xor(acc[j], 4, 64);
        acc[j] += __shfl_xor(acc[j], 8, 64);
    }
    if (eg == 0) {
        float ic = invcnt[n];
        us8 o;
#pragma unroll
        for (int j = 0; j < 8; ++j) o[j] = f2bf(acc[j] * ic);
        *(us8*)(M0s + (size_t)s * NNP * 8 + (size_t)n * 8) = o;
    }
}

// ---------------- gather-mean layers 1,2: slice-major, XCD-pinned, shuffle reduce ----------------
// slice s = blockIdx&7; Hs[s] = [NNP][16] bf16. 16 nodes/block; 8 edge-groups x 2 ch-lanes.

__global__ __launch_bounds__(256) void gather_mean_h(
    const unsigned short* __restrict__ Hs, const int* __restrict__ rowptr,
    const int* __restrict__ csr_src, const float* __restrict__ invcnt,
    unsigned short* __restrict__ Ms) {
    int s = blockIdx.x & 7;
    int chunk = blockIdx.x >> 3;
    int tid = threadIdx.x;
    int n = chunk * 16 + (tid >> 4);
    int l16 = tid & 15;
    int eg = l16 >> 1, cl = l16 & 1;
    int beg = rowptr[n], end = rowptr[n + 1];
    float acc[8] = {};
    const unsigned short* hb = Hs + (size_t)s * NNP * 16 + (size_t)cl * 8;
    int e = beg + eg;
    for (; e + 8 < end; e += 16) {  // 2-deep load pipeline
        int s0 = csr_src[e], s1 = csr_src[e + 8];
        us8 v0 = *(const us8*)(hb + (size_t)s0 * 16);
        us8 v1 = *(const us8*)(hb + (size_t)s1 * 16);
#pragma unroll
        for (int j = 0; j < 8; ++j) acc[j] += bf2f(v0[j]) + bf2f(v1[j]);
    }
    if (e < end) {
        us8 v0 = *(const us8*)(hb + (size_t)csr_src[e] * 16);
#pragma unroll
        for (int j = 0; j < 8; ++j) acc[j] += bf2f(v0[j]);
    }
#pragma unroll
    for (int j = 0; j < 8; ++j) {
        acc[j] += __shfl_xor(acc[j], 2, 64);
        acc[j] += __shfl_xor(acc[j], 4, 64);
        acc[j] += __shfl_xor(acc[j], 8, 64);
    }
    if (eg == 0) {
        float ic = invcnt[n];
        us8 o;
#pragma unroll
        for (int j = 0; j < 8; ++j) o[j] = f2bf(acc[j] * ic);
        *(us8*)(Ms + (size_t)s * NNP * 16 + (size_t)n * 16 + cl * 8) = o;
    }
}

// ---------------- fused MFMA GEMM + bias + L2 norm + (ReLU), slice-major A ----------------
// A channels k<K/2 from Amean slices, k>=K/2 from Ah slices.
// K=128: slice width 8 (slice = ks*4+kb);  K=256: slice width 16 (slice = ks*2+(kb>>1), off (kb&1)*8).

template <int K, bool RELU, bool F32OUT, bool BF16H>
__global__ __launch_bounds__(256) void linear_mfma(
    const unsigned short* __restrict__ Amean, const unsigned short* __restrict__ Ah,
    const unsigned short* __restrict__ Wpk, const float* __restrict__ bias,
    float* __restrict__ outF, unsigned short* __restrict__ HnS /* sliced h out */) {
    constexpr int NK = K / 32;
    __shared__ float rsum[2][32];
    int tid = threadIdx.x;
    int lane = tid & 63, w = tid >> 6;
    int rg = w >> 1, cg = w & 1;
    int r0 = blockIdx.x * 32 + rg * 16;
    int row_l = lane & 15, kb = lane >> 4;
    int row = r0 + row_l;

    const unsigned short* pM;
    const unsigned short* pH;
    if constexpr (K == 128) {
        pM = Amean + (size_t)kb * NNP * 8 + (size_t)row * 8;
        pH = Ah + (size_t)kb * NNP * 8 + (size_t)row * 8;
    } else {
        size_t o = (size_t)(kb >> 1) * NNP * 16 + (size_t)row * 16 + (kb & 1) * 8;
        pM = Amean + o;
        pH = Ah + o;
    }
    const unsigned short* Wp = Wpk + ((size_t)(cg * 4) * 64 + lane) * 8;

    f32x4 acc[4] = {{0.f, 0.f, 0.f, 0.f}, {0.f, 0.f, 0.f, 0.f},
                    {0.f, 0.f, 0.f, 0.f}, {0.f, 0.f, 0.f, 0.f}};
#pragma unroll
    for (int ks = 0; ks < NK; ++ks) {
        short8 a;
        if constexpr (K == 128) {
            a = (ks < 2) ? *(const short8*)(pM + (size_t)ks * 4 * NNP * 8)
                         : *(const short8*)(pH + (size_t)(ks - 2) * 4 * NNP * 8);
        } else {
            a = (ks < 4) ? *(const short8*)(pM + (size_t)ks * 2 * NNP * 16)
                         : *(const short8*)(pH + (size_t)(ks - 4) * 2 * NNP * 16);
        }
#pragma unroll
        for (int t = 0; t < 4; ++t) {
            short8 b = *(const short8*)(Wp + ((size_t)ks * 8 + t) * 64 * 8);
            acc[t] = __builtin_amdgcn_mfma_f32_16x16x32_bf16(a, b, acc[t], 0, 0, 0);
        }
    }

    float sq[4] = {0.f, 0.f, 0.f, 0.f};
#pragma unroll
    for (int t = 0; t < 4; ++t) {
        float bv = bias[cg * 64 + t * 16 + row_l];
#pragma unroll
        for (int r = 0; r < 4; ++r) {
            acc[t][r] += bv;
            sq[r] = fmaf(acc[t][r], acc[t][r], sq[r]);
        }
    }
#pragma unroll
    for (int off = 1; off < 16; off <<= 1)
#pragma unroll
        for (int r = 0; r < 4; ++r) sq[r] += __shfl_xor(sq[r], off, 64);

    if (row_l == 0) {
#pragma unroll
        for (int r = 0; r < 4; ++r) rsum[cg][rg * 16 + kb * 4 + r] = sq[r];
    }
    __syncthreads();  // also orders all A reads before the BF16H in-place writes

    int rbase = rg * 16 + kb * 4;
#pragma unroll
    for (int r = 0; r < 4; ++r) {
        int orow = r0 + kb * 4 + r;
        if (orow >= NN) continue;
        float n2 = rsum[0][rbase + r] + rsum[1][rbase + r];
        float inv = 1.0f / fmaxf(sqrtf(n2), 1e-12f);
#pragma unroll
        for (int t = 0; t < 4; ++t) {
            float v = acc[t][r] * inv;
            if (RELU) v = fmaxf(v, 0.f);
            if (F32OUT) outF[(size_t)orow * HD + cg * 64 + t * 16 + row_l] = v;
            if (BF16H)  // slice = cg*4+t, offset row_l
                HnS[(size_t)(cg * 4 + t) * NNP * 16 + (size_t)orow * 16 + row_l] = f2bf(v);
        }
    }
}

// ---------------- launch ----------------

static inline size_t align256(size_t x) { return (x + 255) & ~(size_t)255; }

extern "C" void kernel_launch(void* const* d_in, const int* in_sizes, int n_in,
                              void* d_out, int out_size, void* d_ws, size_t ws_size,
                              hipStream_t stream) {
    const float* x   = (const float*)d_in[0];
    const int*   ei  = (const int*)d_in[1];
    const float* Wl0 = (const float*)d_in[2];
    const float* bl0 = (const float*)d_in[3];
    const float* Wr0 = (const float*)d_in[4];
    const float* Wl1 = (const float*)d_in[5];
    const float* bl1 = (const float*)d_in[6];
    const float* Wr1 = (const float*)d_in[7];
    const float* Wl2 = (const float*)d_in[8];
    const float* bl2 = (const float*)d_in[9];
    const float* Wr2 = (const float*)d_in[10];

    const int* src = ei;
    const int* dst = ei + NE;

    // workspace carve-up
    char* p = (char*)d_ws;
    size_t off = 0;
    int* meta = (int*)(p + off);            off = align256(off + 512 * 4);
    int* bbase = (int*)(p + off);           off = align256(off + 256 * 4);
    int* rowptr = (int*)(p + off);          off = align256(off + (size_t)(NN + 1) * 4);
    int* csr_src = (int*)(p + off);         off = align256(off + (size_t)NE * 4);
    float* invcnt = (float*)(p + off);      off = align256(off + (size_t)NN * 4);
    int2* pairs = (int2*)(p + off);         off = align256(off + (size_t)NE * 8);
    unsigned short* Xs  = (unsigned short*)(p + off);  off = align256(off + (size_t)8 * NNP * 8 * 2);
    unsigned short* M0s = (unsigned short*)(p + off);  off = align256(off + (size_t)8 * NNP * 8 * 2);
    unsigned short* Ms  = (unsigned short*)(p + off);  off = align256(off + (size_t)8 * NNP * 16 * 2);
    unsigned short* Hs  = (unsigned short*)(p + off);  off = align256(off + (size_t)8 * NNP * 16 * 2);
    unsigned short* Wpk0 = (unsigned short*)(p + off); off = align256(off + (size_t)2 * DIN * HD * 2);
    unsigned short* Wpk1 = (unsigned short*)(p + off); off = align256(off + (size_t)2 * HD * HD * 2);
    unsigned short* Wpk2 = (unsigned short*)(p + off); off = align256(off + (size_t)2 * HD * HD * 2);
    (void)ws_size; (void)n_in; (void)in_sizes; (void)out_size;

    int* bcnt = meta;
    int* bfill = meta + 256;
    float* out = (float*)d_out;

    // prep first (also zeroes meta, stream-ordered before bucket_count)
    prep<<<PACK_BLOCKS + CONV_BLOCKS + 1, 256, 0, stream>>>(
        Wl0, Wr0, Wl1, Wr1, Wl2, Wr2, Wpk0, Wpk1, Wpk2, x, Xs, meta);

    // CSR build: two-level LDS counting sort
    bucket_count<<<SB, 256, 0, stream>>>(dst, bcnt);
    bucket_scan<<<1, 256, 0, stream>>>(bcnt, bbase, rowptr);
    bucket_scatter<<<SB, 256, 0, stream>>>(src, dst, bbase, bfill, pairs);
    build_csr<<<NBUK, 256, 0, stream>>>(pairs, bbase, rowptr, invcnt, csr_src);

    const int LG = NNP / 32;        // 1563
    const int GG = 8 * NCHUNK;      // 25000 sliced gather blocks (slice = blockIdx & 7)

    // layer 0: gather x slices -> M0s; GEMM K=128 -> h0 into Hs (sliced)
    gather_mean_x<<<GG, 256, 0, stream>>>(rowptr, csr_src, invcnt, Xs, M0s);
    linear_mfma<2 * DIN, true, false, true><<<LG, 256, 0, stream>>>(
        M0s, Xs, Wpk0, bl0, nullptr, Hs);

    // layer 1: gather h0 slices -> Ms; GEMM K=256 -> h1 into Hs (row-exclusive in-place)
    gather_mean_h<<<GG, 256, 0, stream>>>(Hs, rowptr, csr_src, invcnt, Ms);
    linear_mfma<2 * HD, true, false, true><<<LG, 256, 0, stream>>>(
        Ms, Hs, Wpk1, bl1, nullptr, Hs);

    // layer 2: gather h1 slices -> Ms; GEMM K=256 -> f32 d_out
    gather_mean_h<<<GG, 256, 0, stream>>>(Hs, rowptr, csr_src, invcnt, Ms);
    linear_mfma<2 * HD, false, true, false><<<LG, 256, 0, stream>>>(
        Ms, Hs, Wpk2, bl2, out, nullptr);
}

// Round 12
// 190.279 us; speedup vs baseline: 1.5495x; 1.0460x over previous
//
#include <hip/hip_runtime.h>

#define NN 50000
#define NNP 50016   // 1563 * 32, padded rows for the GEMM
#define NE 800000
#define DIN 64
#define HD 128
#define NBUK 196            // ceil(NN/256) coarse buckets (dst>>8)
#define SB 196              // ceil(NE/4096) scatter chunks
#define BCAP 12288          // build_csr LDS capacity (edges per bucket fast path)

typedef __attribute__((ext_vector_type(8))) short short8;
typedef __attribute__((ext_vector_type(4))) float f32x4;
typedef __attribute__((ext_vector_type(4))) unsigned short us4;
typedef __attribute__((ext_vector_type(8))) unsigned short us8;

__device__ __forceinline__ unsigned short f2bf(float f) {
    unsigned int u = __float_as_uint(f);
    u = (u + 0x7FFFu + ((u >> 16) & 1u)) >> 16;
    return (unsigned short)u;
}
__device__ __forceinline__ float bf2f(unsigned short u) {
    return __uint_as_float(((unsigned int)u) << 16);
}

// inclusive Hillis-Steele scan over a[256]; all 256 threads must execute
#define LDS_SCAN256(a, t)                                 \
    for (int off_ = 1; off_ < 256; off_ <<= 1) {          \
        int add_ = ((t) >= off_) ? (a)[(t) - off_] : 0;   \
        __syncthreads();                                  \
        (a)[t] += add_;                                   \
        __syncthreads();                                  \
    }

// ---------------- CSR via two-level LDS counting sort (packed pairs) ----------------
// packed edge: (dst&255)<<24 | src   (src < 2^17 fits low 24 bits)

__global__ __launch_bounds__(256) void bucket_count(const int* __restrict__ dst,
                                                    int* __restrict__ bcnt) {
    __shared__ int lc[256];
    int t = threadIdx.x;
    lc[t] = 0;
    __syncthreads();
    int base = blockIdx.x * 4096 + t * 16;
#pragma unroll
    for (int j = 0; j < 4; ++j) {
        int e = base + j * 4;
        if (e < NE) {
            int4 d = *(const int4*)(dst + e);
            atomicAdd(&lc[d.x >> 8], 1);
            atomicAdd(&lc[d.y >> 8], 1);
            atomicAdd(&lc[d.z >> 8], 1);
            atomicAdd(&lc[d.w >> 8], 1);
        }
    }
    __syncthreads();
    if (t < NBUK && lc[t] > 0) atomicAdd(&bcnt[t], lc[t]);
}

__global__ __launch_bounds__(256) void bucket_scan(const int* __restrict__ bcnt,
                                                   int* __restrict__ bbase,
                                                   int* __restrict__ rowptr) {
    __shared__ int sh[256];
    int t = threadIdx.x;
    int v = (t < NBUK) ? bcnt[t] : 0;
    sh[t] = v;
    __syncthreads();
    LDS_SCAN256(sh, t);
    if (t < NBUK) bbase[t] = sh[t] - v;   // exclusive
    if (t == NBUK - 1) bbase[NBUK] = sh[t];
    if (t == 0) rowptr[NN] = NE;
}

__global__ __launch_bounds__(256) void bucket_scatter(
    const int* __restrict__ src, const int* __restrict__ dst,
    const int* __restrict__ bbase, int* __restrict__ bfill,
    int* __restrict__ pairs) {
    __shared__ int cnt[256];
    __shared__ int incl[256];
    __shared__ int lfill[256];
    __shared__ int rung[256];
    __shared__ int buf[4096];
    int t = threadIdx.x;
    cnt[t] = 0;
    lfill[t] = 0;
    __syncthreads();
    int base = blockIdx.x * 4096 + t * 16;
#pragma unroll
    for (int j = 0; j < 4; ++j) {
        int e = base + j * 4;
        if (e < NE) {
            int4 d = *(const int4*)(dst + e);
            atomicAdd(&cnt[d.x >> 8], 1);
            atomicAdd(&cnt[d.y >> 8], 1);
            atomicAdd(&cnt[d.z >> 8], 1);
            atomicAdd(&cnt[d.w >> 8], 1);
        }
    }
    __syncthreads();
    incl[t] = cnt[t];
    __syncthreads();
    LDS_SCAN256(incl, t);
    int c = cnt[t];
    if (t < NBUK && c > 0) rung[t] = bbase[t] + atomicAdd(&bfill[t], c);
    __syncthreads();
#pragma unroll
    for (int j = 0; j < 4; ++j) {
        int e = base + j * 4;
        if (e < NE) {
            int4 s4 = *(const int4*)(src + e);
            int4 d4 = *(const int4*)(dst + e);
            int ss[4] = {s4.x, s4.y, s4.z, s4.w};
            int dd[4] = {d4.x, d4.y, d4.z, d4.w};
#pragma unroll
            for (int q = 0; q < 4; ++q) {
                int k = dd[q] >> 8;
                int p = (incl[k] - cnt[k]) + atomicAdd(&lfill[k], 1);
                buf[p] = ((dd[q] & 255) << 24) | ss[q];
            }
        }
    }
    __syncthreads();
    int n = min(4096, NE - blockIdx.x * 4096);
    for (int i = t; i < n; i += 256) {
        int pr = buf[i];
        int k = (((unsigned)pr >> 24) | ((blockIdx.x * 0) & 0));  // dstlow only; bucket from position
        // bucket index must come from dst>>8; recover via rung mapping: we stored runs per bucket k,
        // so recompute k from the original histogram position:
        // i lies in bucket k where incl[k]-cnt[k] <= i < incl[k]; find via dstlow? Not derivable.
        // Instead: store bucket in bits 17..23 is not possible (needs 8 bits). Use binary search over incl.
        int lo = 0, hi = 255;
        while (lo < hi) {  // first k with incl[k] > i
            int mid = (lo + hi) >> 1;
            if (incl[mid] > i) hi = mid; else lo = mid + 1;
        }
        k = lo;
        pairs[rung[k] + (i - (incl[k] - cnt[k]))] = pr;
    }
}

__global__ __launch_bounds__(256) void build_csr(
    const int* __restrict__ pairs, const int* __restrict__ bbase,
    int* __restrict__ rowptr, float* __restrict__ invcnt,
    int* __restrict__ csr_src) {
    __shared__ int cnt[256];
    __shared__ int incl[256];
    __shared__ int lfill[256];
    __shared__ int sbuf[BCAP];
    int b = blockIdx.x, t = threadIdx.x;
    int pbeg = bbase[b], pend = bbase[b + 1];
    int sz = pend - pbeg;
    cnt[t] = 0;
    lfill[t] = 0;
    __syncthreads();
    for (int i = t; i < sz; i += 256)
        atomicAdd(&cnt[(unsigned)pairs[pbeg + i] >> 24], 1);
    __syncthreads();
    incl[t] = cnt[t];
    __syncthreads();
    LDS_SCAN256(incl, t);
    int node = b * 256 + t;
    int c = cnt[t];
    if (node < NN) {
        rowptr[node] = pbeg + incl[t] - c;
        invcnt[node] = 1.0f / (float)(c > 0 ? c : 1);
    }
    if (sz <= BCAP) {
        for (int i = t; i < sz; i += 256) {
            int pr = pairs[pbeg + i];
            int ld = (unsigned)pr >> 24;
            sbuf[(incl[ld] - cnt[ld]) + atomicAdd(&lfill[ld], 1)] = pr & 0xFFFFFF;
        }
        __syncthreads();
        for (int i = t; i < sz; i += 256) csr_src[pbeg + i] = sbuf[i];
    } else {
        for (int i = t; i < sz; i += 256) {
            int pr = pairs[pbeg + i];
            int ld = (unsigned)pr >> 24;
            csr_src[pbeg + (incl[ld] - cnt[ld]) + atomicAdd(&lfill[ld], 1)] = pr & 0xFFFFFF;
        }
    }
}

// ---------------- prep: zero meta + pack weights + x -> bf16 sliced ----------------

__device__ __forceinline__ void pack_one(const float* Wl, const float* Wr, int D,
                                         unsigned short* Wpk, int i) {
    int j = i & 7;
    int lane = (i >> 3) & 63;
    int ct = (i >> 9) & 7;
    int ks = i >> 12;
    int k = ks * 32 + ((lane >> 4) << 3) + j;
    int c = ct * 16 + (lane & 15);
    float v = (k < D) ? Wl[c * D + k] : Wr[c * D + (k - D)];
    Wpk[i] = f2bf(v);
}

#define PACK_BLOCKS 320   // 81920/256
#define CONV_BLOCKS 3125  // NN*16/256

__global__ __launch_bounds__(256) void prep(
    const float* __restrict__ Wl0, const float* __restrict__ Wr0,
    const float* __restrict__ Wl1, const float* __restrict__ Wr1,
    const float* __restrict__ Wl2, const float* __restrict__ Wr2,
    unsigned short* __restrict__ Wpk0, unsigned short* __restrict__ Wpk1,
    unsigned short* __restrict__ Wpk2,
    const float* __restrict__ x, unsigned short* __restrict__ Xs,
    int* __restrict__ meta) {
    const int S0 = 2 * DIN * HD;   // 16384
    const int S12 = 2 * HD * HD;   // 32768
    int b = blockIdx.x;
    int t = threadIdx.x;
    if (b < PACK_BLOCKS) {
        int i = b * 256 + t;
        if (i < S0) { pack_one(Wl0, Wr0, DIN, Wpk0, i); return; }
        int j = i - S0;
        if (j < S12) { pack_one(Wl1, Wr1, HD, Wpk1, j); return; }
        int m = j - S12;
        if (m < S12) pack_one(Wl2, Wr2, HD, Wpk2, m);
        return;
    }
    if (b < PACK_BLOCKS + CONV_BLOCKS) {
        // x f32 [NN][64] -> bf16 slice-major Xs[8][NNP][8]
        int i = (b - PACK_BLOCKS) * 256 + t;   // < NN*16
        int row = i >> 4, c4 = i & 15;
        float4 v = ((const float4*)(x + (size_t)row * DIN))[c4];
        us4 o = {f2bf(v.x), f2bf(v.y), f2bf(v.z), f2bf(v.w)};
        *(us4*)(Xs + (size_t)(c4 >> 1) * NNP * 8 + (size_t)row * 8 + (c4 & 1) * 4) = o;
        return;
    }
    // last block: zero meta (bcnt[256] + bfill[256]) — 256 threads cover 512 ints
    meta[t] = 0;
    meta[t + 256] = 0;
}

// ---------------- gather-mean layer 0: slice-major, 4-deep pipeline ----------------
// slice s = blockIdx&7; Xs[s] = [NNP][8] bf16. 64 nodes/block, 4 lanes/node (4 edge-groups).

__global__ __launch_bounds__(256) void gather_mean_x(
    const int* __restrict__ rowptr, const int* __restrict__ csr_src,
    const float* __restrict__ invcnt, const unsigned short* __restrict__ Xs,
    unsigned short* __restrict__ M0s) {
    int s = blockIdx.x & 7;
    int chunk = blockIdx.x >> 3;
    int tid = threadIdx.x;
    int n = chunk * 64 + (tid >> 2);
    if (n >= NN) return;
    int eg = tid & 3;   // 4 edge groups, each lane reads full 16B slice row
    int beg = rowptr[n], end = rowptr[n + 1];
    float acc[8] = {};
    const unsigned short* hb = Xs + (size_t)s * NNP * 8;
    int e = beg + eg;
    for (; e + 12 < end; e += 16) {  // 4-deep load pipeline
        int i0 = csr_src[e], i1 = csr_src[e + 4], i2 = csr_src[e + 8], i3 = csr_src[e + 12];
        us8 v0 = *(const us8*)(hb + (size_t)i0 * 8);
        us8 v1 = *(const us8*)(hb + (size_t)i1 * 8);
        us8 v2 = *(const us8*)(hb + (size_t)i2 * 8);
        us8 v3 = *(const us8*)(hb + (size_t)i3 * 8);
#pragma unroll
        for (int j = 0; j < 8; ++j)
            acc[j] += (bf2f(v0[j]) + bf2f(v1[j])) + (bf2f(v2[j]) + bf2f(v3[j]));
    }
    for (; e < end; e += 4) {
        us8 v0 = *(const us8*)(hb + (size_t)csr_src[e] * 8);
#pragma unroll
        for (int j = 0; j < 8; ++j) acc[j] += bf2f(v0[j]);
    }
#pragma unroll
    for (int j = 0; j < 8; ++j) {
        acc[j] += __shfl_xor(acc[j], 1, 64);
        acc[j] += __shfl_xor(acc[j], 2, 64);
    }
    if (eg == 0) {
        float ic = invcnt[n];
        us8 o;
#pragma unroll
        for (int j = 0; j < 8; ++j) o[j] = f2bf(acc[j] * ic);
        *(us8*)(M0s + (size_t)s * NNP * 8 + (size_t)n * 8) = o;
    }
}

// ---------------- gather-mean layers 1,2: slice-major, 4-deep pipeline ----------------
// slice s = blockIdx&7; Hs[s] = [NNP][16] bf16. 32 nodes/block; 4 edge-groups x 2 ch-lanes.

__global__ __launch_bounds__(256) void gather_mean_h(
    const unsigned short* __restrict__ Hs, const int* __restrict__ rowptr,
    const int* __restrict__ csr_src, const float* __restrict__ invcnt,
    unsigned short* __restrict__ Ms) {
    int s = blockIdx.x & 7;
    int chunk = blockIdx.x >> 3;
    int tid = threadIdx.x;
    int n = chunk * 32 + (tid >> 3);
    if (n >= NN) return;
    int l8 = tid & 7;
    int eg = l8 >> 1, cl = l8 & 1;   // 4 edge-groups x 2 ch-lanes
    int beg = rowptr[n], end = rowptr[n + 1];
    float acc[8] = {};
    const unsigned short* hb = Hs + (size_t)s * NNP * 16 + (size_t)cl * 8;
    int e = beg + eg;
    for (; e + 12 < end; e += 16) {  // 4-deep load pipeline
        int i0 = csr_src[e], i1 = csr_src[e + 4], i2 = csr_src[e + 8], i3 = csr_src[e + 12];
        us8 v0 = *(const us8*)(hb + (size_t)i0 * 16);
        us8 v1 = *(const us8*)(hb + (size_t)i1 * 16);
        us8 v2 = *(const us8*)(hb + (size_t)i2 * 16);
        us8 v3 = *(const us8*)(hb + (size_t)i3 * 16);
#pragma unroll
        for (int j = 0; j < 8; ++j)
            acc[j] += (bf2f(v0[j]) + bf2f(v1[j])) + (bf2f(v2[j]) + bf2f(v3[j]));
    }
    for (; e < end; e += 4) {
        us8 v0 = *(const us8*)(hb + (size_t)csr_src[e] * 16);
#pragma unroll
        for (int j = 0; j < 8; ++j) acc[j] += bf2f(v0[j]);
    }
#pragma unroll
    for (int j = 0; j < 8; ++j) {
        acc[j] += __shfl_xor(acc[j], 2, 64);
        acc[j] += __shfl_xor(acc[j], 4, 64);
    }
    if (eg == 0) {
        float ic = invcnt[n];
        us8 o;
#pragma unroll
        for (int j = 0; j < 8; ++j) o[j] = f2bf(acc[j] * ic);
        *(us8*)(Ms + (size_t)s * NNP * 16 + (size_t)n * 16 + cl * 8) = o;
    }
}

// ---------------- fused MFMA GEMM + bias + L2 norm + (ReLU), slice-major A ----------------

template <int K, bool RELU, bool F32OUT, bool BF16H>
__global__ __launch_bounds__(256) void linear_mfma(
    const unsigned short* __restrict__ Amean, const unsigned short* __restrict__ Ah,
    const unsigned short* __restrict__ Wpk, const float* __restrict__ bias,
    float* __restrict__ outF, unsigned short* __restrict__ HnS /* sliced h out */) {
    constexpr int NK = K / 32;
    __shared__ float rsum[2][32];
    int tid = threadIdx.x;
    int lane = tid & 63, w = tid >> 6;
    int rg = w >> 1, cg = w & 1;
    int r0 = blockIdx.x * 32 + rg * 16;
    int row_l = lane & 15, kb = lane >> 4;
    int row = r0 + row_l;

    const unsigned short* pM;
    const unsigned short* pH;
    if constexpr (K == 128) {
        pM = Amean + (size_t)kb * NNP * 8 + (size_t)row * 8;
        pH = Ah + (size_t)kb * NNP * 8 + (size_t)row * 8;
    } else {
        size_t o = (size_t)(kb >> 1) * NNP * 16 + (size_t)row * 16 + (kb & 1) * 8;
        pM = Amean + o;
        pH = Ah + o;
    }
    const unsigned short* Wp = Wpk + ((size_t)(cg * 4) * 64 + lane) * 8;

    f32x4 acc[4] = {{0.f, 0.f, 0.f, 0.f}, {0.f, 0.f, 0.f, 0.f},
                    {0.f, 0.f, 0.f, 0.f}, {0.f, 0.f, 0.f, 0.f}};
#pragma unroll
    for (int ks = 0; ks < NK; ++ks) {
        short8 a;
        if constexpr (K == 128) {
            a = (ks < 2) ? *(const short8*)(pM + (size_t)ks * 4 * NNP * 8)
                         : *(const short8*)(pH + (size_t)(ks - 2) * 4 * NNP * 8);
        } else {
            a = (ks < 4) ? *(const short8*)(pM + (size_t)ks * 2 * NNP * 16)
                         : *(const short8*)(pH + (size_t)(ks - 4) * 2 * NNP * 16);
        }
#pragma unroll
        for (int t = 0; t < 4; ++t) {
            short8 b = *(const short8*)(Wp + ((size_t)ks * 8 + t) * 64 * 8);
            acc[t] = __builtin_amdgcn_mfma_f32_16x16x32_bf16(a, b, acc[t], 0, 0, 0);
        }
    }

    float sq[4] = {0.f, 0.f, 0.f, 0.f};
#pragma unroll
    for (int t = 0; t < 4; ++t) {
        float bv = bias[cg * 64 + t * 16 + row_l];
#pragma unroll
        for (int r = 0; r < 4; ++r) {
            acc[t][r] += bv;
            sq[r] = fmaf(acc[t][r], acc[t][r], sq[r]);
        }
    }
#pragma unroll
    for (int off = 1; off < 16; off <<= 1)
#pragma unroll
        for (int r = 0; r < 4; ++r) sq[r] += __shfl_xor(sq[r], off, 64);

    if (row_l == 0) {
#pragma unroll
        for (int r = 0; r < 4; ++r) rsum[cg][rg * 16 + kb * 4 + r] = sq[r];
    }
    __syncthreads();  // also orders all A reads before the BF16H in-place writes

    int rbase = rg * 16 + kb * 4;
#pragma unroll
    for (int r = 0; r < 4; ++r) {
        int orow = r0 + kb * 4 + r;
        if (orow >= NN) continue;
        float n2 = rsum[0][rbase + r] + rsum[1][rbase + r];
        float inv = 1.0f / fmaxf(sqrtf(n2), 1e-12f);
#pragma unroll
        for (int t = 0; t < 4; ++t) {
            float v = acc[t][r] * inv;
            if (RELU) v = fmaxf(v, 0.f);
            if (F32OUT) outF[(size_t)orow * HD + cg * 64 + t * 16 + row_l] = v;
            if (BF16H)  // slice = cg*4+t, offset row_l
                HnS[(size_t)(cg * 4 + t) * NNP * 16 + (size_t)orow * 16 + row_l] = f2bf(v);
        }
    }
}

// ---------------- launch ----------------

static inline size_t align256(size_t x) { return (x + 255) & ~(size_t)255; }

extern "C" void kernel_launch(void* const* d_in, const int* in_sizes, int n_in,
                              void* d_out, int out_size, void* d_ws, size_t ws_size,
                              hipStream_t stream) {
    const float* x   = (const float*)d_in[0];
    const int*   ei  = (const int*)d_in[1];
    const float* Wl0 = (const float*)d_in[2];
    const float* bl0 = (const float*)d_in[3];
    const float* Wr0 = (const float*)d_in[4];
    const float* Wl1 = (const float*)d_in[5];
    const float* bl1 = (const float*)d_in[6];
    const float* Wr1 = (const float*)d_in[7];
    const float* Wl2 = (const float*)d_in[8];
    const float* bl2 = (const float*)d_in[9];
    const float* Wr2 = (const float*)d_in[10];

    const int* src = ei;
    const int* dst = ei + NE;

    // workspace carve-up
    char* p = (char*)d_ws;
    size_t off = 0;
    int* meta = (int*)(p + off);            off = align256(off + 512 * 4);
    int* bbase = (int*)(p + off);           off = align256(off + 256 * 4);
    int* rowptr = (int*)(p + off);          off = align256(off + (size_t)(NN + 1) * 4);
    int* csr_src = (int*)(p + off);         off = align256(off + (size_t)NE * 4);
    float* invcnt = (float*)(p + off);      off = align256(off + (size_t)NN * 4);
    int* pairs = (int*)(p + off);           off = align256(off + (size_t)NE * 4);
    unsigned short* Xs  = (unsigned short*)(p + off);  off = align256(off + (size_t)8 * NNP * 8 * 2);
    unsigned short* M0s = (unsigned short*)(p + off);  off = align256(off + (size_t)8 * NNP * 8 * 2);
    unsigned short* Ms  = (unsigned short*)(p + off);  off = align256(off + (size_t)8 * NNP * 16 * 2);
    unsigned short* Hs  = (unsigned short*)(p + off);  off = align256(off + (size_t)8 * NNP * 16 * 2);
    unsigned short* Wpk0 = (unsigned short*)(p + off); off = align256(off + (size_t)2 * DIN * HD * 2);
    unsigned short* Wpk1 = (unsigned short*)(p + off); off = align256(off + (size_t)2 * HD * HD * 2);
    unsigned short* Wpk2 = (unsigned short*)(p + off); off = align256(off + (size_t)2 * HD * HD * 2);
    (void)ws_size; (void)n_in; (void)in_sizes; (void)out_size;

    int* bcnt = meta;
    int* bfill = meta + 256;
    float* out = (float*)d_out;

    // prep first (also zeroes meta, stream-ordered before bucket_count)
    prep<<<PACK_BLOCKS + CONV_BLOCKS + 1, 256, 0, stream>>>(
        Wl0, Wr0, Wl1, Wr1, Wl2, Wr2, Wpk0, Wpk1, Wpk2, x, Xs, meta);

    // CSR build: two-level LDS counting sort (packed pairs)
    bucket_count<<<SB, 256, 0, stream>>>(dst, bcnt);
    bucket_scan<<<1, 256, 0, stream>>>(bcnt, bbase, rowptr);
    bucket_scatter<<<SB, 256, 0, stream>>>(src, dst, bbase, bfill, pairs);
    build_csr<<<NBUK, 256, 0, stream>>>(pairs, bbase, rowptr, invcnt, csr_src);

    const int LG = NNP / 32;          // 1563
    const int GGX = 8 * 782;          // 64 nodes/block
    const int GGH = 8 * 1563;         // 32 nodes/block

    // layer 0: gather x slices -> M0s; GEMM K=128 -> h0 into Hs (sliced)
    gather_mean_x<<<GGX, 256, 0, stream>>>(rowptr, csr_src, invcnt, Xs, M0s);
    linear_mfma<2 * DIN, true, false, true><<<LG, 256, 0, stream>>>(
        M0s, Xs, Wpk0, bl0, nullptr, Hs);

    // layer 1: gather h0 slices -> Ms; GEMM K=256 -> h1 into Hs (row-exclusive in-place)
    gather_mean_h<<<GGH, 256, 0, stream>>>(Hs, rowptr, csr_src, invcnt, Ms);
    linear_mfma<2 * HD, true, false, true><<<LG, 256, 0, stream>>>(
        Ms, Hs, Wpk1, bl1, nullptr, Hs);

    // layer 2: gather h1 slices -> Ms; GEMM K=256 -> f32 d_out
    gather_mean_h<<<GGH, 256, 0, stream>>>(Hs, rowptr, csr_src, invcnt, Ms);
    linear_mfma<2 * HD, false, true, false><<<LG, 256, 0, stream>>>(
        Ms, Hs, Wpk2, bl2, out, nullptr);
}

// Round 13
// 166.786 us; speedup vs baseline: 1.7678x; 1.1409x over previous
//
#include <hip/hip_runtime.h>

#define NN 50000
#define NNP 50016   // 1563 * 32, padded rows for the GEMM
#define NE 800000
#define DIN 64
#define HD 128
#define NBUK 196            // ceil(NN/256) coarse buckets (dst>>8)
#define SB 196              // ceil(NE/4096) scatter chunks
#define BCAP 12288          // build_csr LDS capacity (edges per bucket fast path)

typedef __attribute__((ext_vector_type(8))) short short8;
typedef __attribute__((ext_vector_type(4))) float f32x4;
typedef __attribute__((ext_vector_type(4))) unsigned short us4;
typedef __attribute__((ext_vector_type(8))) unsigned short us8;

__device__ __forceinline__ unsigned short f2bf(float f) {
    unsigned int u = __float_as_uint(f);
    u = (u + 0x7FFFu + ((u >> 16) & 1u)) >> 16;
    return (unsigned short)u;
}
__device__ __forceinline__ float bf2f(unsigned short u) {
    return __uint_as_float(((unsigned int)u) << 16);
}

// inclusive Hillis-Steele scan over a[256]; all 256 threads must execute
#define LDS_SCAN256(a, t)                                 \
    for (int off_ = 1; off_ < 256; off_ <<= 1) {          \
        int add_ = ((t) >= off_) ? (a)[(t) - off_] : 0;   \
        __syncthreads();                                  \
        (a)[t] += add_;                                   \
        __syncthreads();                                  \
    }

// ---------------- CSR via two-level LDS counting sort ----------------
// packed edge: (dst&255)<<24 | src  (src < 2^17); bucket id kept in LDS byte array.

__global__ __launch_bounds__(256) void bucket_count(const int* __restrict__ dst,
                                                    int* __restrict__ bcnt) {
    __shared__ int lc[256];
    int t = threadIdx.x;
    lc[t] = 0;
    __syncthreads();
    int base = blockIdx.x * 4096 + t * 16;
#pragma unroll
    for (int j = 0; j < 4; ++j) {
        int e = base + j * 4;
        if (e < NE) {
            int4 d = *(const int4*)(dst + e);
            atomicAdd(&lc[d.x >> 8], 1);
            atomicAdd(&lc[d.y >> 8], 1);
            atomicAdd(&lc[d.z >> 8], 1);
            atomicAdd(&lc[d.w >> 8], 1);
        }
    }
    __syncthreads();
    if (t < NBUK && lc[t] > 0) atomicAdd(&bcnt[t], lc[t]);
}

__global__ __launch_bounds__(256) void bucket_scan(const int* __restrict__ bcnt,
                                                   int* __restrict__ bbase,
                                                   int* __restrict__ rowptr) {
    __shared__ int sh[256];
    int t = threadIdx.x;
    int v = (t < NBUK) ? bcnt[t] : 0;
    sh[t] = v;
    __syncthreads();
    LDS_SCAN256(sh, t);
    if (t < NBUK) bbase[t] = sh[t] - v;   // exclusive
    if (t == NBUK - 1) bbase[NBUK] = sh[t];
    if (t == 0) rowptr[NN] = NE;
}

__global__ __launch_bounds__(256) void bucket_scatter(
    const int* __restrict__ src, const int* __restrict__ dst,
    const int* __restrict__ bbase, int* __restrict__ bfill,
    int* __restrict__ pairs) {
    __shared__ int cnt[256];
    __shared__ int incl[256];
    __shared__ int lfill[256];
    __shared__ int rung[256];
    __shared__ int buf[4096];
    __shared__ unsigned char bk[4096];
    int t = threadIdx.x;
    cnt[t] = 0;
    lfill[t] = 0;
    __syncthreads();
    int base = blockIdx.x * 4096 + t * 16;
    // phase A: local bucket histogram
#pragma unroll
    for (int j = 0; j < 4; ++j) {
        int e = base + j * 4;
        if (e < NE) {
            int4 d = *(const int4*)(dst + e);
            atomicAdd(&cnt[d.x >> 8], 1);
            atomicAdd(&cnt[d.y >> 8], 1);
            atomicAdd(&cnt[d.z >> 8], 1);
            atomicAdd(&cnt[d.w >> 8], 1);
        }
    }
    __syncthreads();
    incl[t] = cnt[t];
    __syncthreads();
    LDS_SCAN256(incl, t);
    // phase B: allocate one global run per non-empty bucket
    int c = cnt[t];
    if (t < NBUK && c > 0) rung[t] = bbase[t] + atomicAdd(&bfill[t], c);
    __syncthreads();
    // phase C: local scatter into LDS, grouped by bucket (packed value + bucket byte)
#pragma unroll
    for (int j = 0; j < 4; ++j) {
        int e = base + j * 4;
        if (e < NE) {
            int4 s4 = *(const int4*)(src + e);
            int4 d4 = *(const int4*)(dst + e);
            int ss[4] = {s4.x, s4.y, s4.z, s4.w};
            int dd[4] = {d4.x, d4.y, d4.z, d4.w};
#pragma unroll
            for (int q = 0; q < 4; ++q) {
                int k = dd[q] >> 8;
                int p = (incl[k] - cnt[k]) + atomicAdd(&lfill[k], 1);
                buf[p] = ((dd[q] & 255) << 24) | ss[q];
                bk[p] = (unsigned char)k;
            }
        }
    }
    __syncthreads();
    // phase D: coalesced run writes
    int n = min(4096, NE - blockIdx.x * 4096);
    for (int i = t; i < n; i += 256) {
        int k = bk[i];
        pairs[rung[k] + (i - (incl[k] - cnt[k]))] = buf[i];
    }
}

__global__ __launch_bounds__(256) void build_csr(
    const int* __restrict__ pairs, const int* __restrict__ bbase,
    int* __restrict__ rowptr, float* __restrict__ invcnt,
    int* __restrict__ csr_src) {
    __shared__ int cnt[256];
    __shared__ int incl[256];
    __shared__ int lfill[256];
    __shared__ int sbuf[BCAP];
    int b = blockIdx.x, t = threadIdx.x;
    int pbeg = bbase[b], pend = bbase[b + 1];
    int sz = pend - pbeg;
    cnt[t] = 0;
    lfill[t] = 0;
    __syncthreads();
    for (int i = t; i < sz; i += 256)
        atomicAdd(&cnt[(unsigned)pairs[pbeg + i] >> 24], 1);
    __syncthreads();
    incl[t] = cnt[t];
    __syncthreads();
    LDS_SCAN256(incl, t);
    int node = b * 256 + t;
    int c = cnt[t];
    if (node < NN) {
        rowptr[node] = pbeg + incl[t] - c;
        invcnt[node] = 1.0f / (float)(c > 0 ? c : 1);
    }
    if (sz <= BCAP) {
        for (int i = t; i < sz; i += 256) {
            int pr = pairs[pbeg + i];
            int ld = (unsigned)pr >> 24;
            sbuf[(incl[ld] - cnt[ld]) + atomicAdd(&lfill[ld], 1)] = pr & 0xFFFFFF;
        }
        __syncthreads();
        for (int i = t; i < sz; i += 256) csr_src[pbeg + i] = sbuf[i];
    } else {  // safety fallback
        for (int i = t; i < sz; i += 256) {
            int pr = pairs[pbeg + i];
            int ld = (unsigned)pr >> 24;
            csr_src[pbeg + (incl[ld] - cnt[ld]) + atomicAdd(&lfill[ld], 1)] = pr & 0xFFFFFF;
        }
    }
}

// ---------------- prep: zero meta + pack weights + x -> bf16 into A0 h-half ----------------

__device__ __forceinline__ void pack_one(const float* Wl, const float* Wr, int D,
                                         unsigned short* Wpk, int i) {
    int j = i & 7;
    int lane = (i >> 3) & 63;
    int ct = (i >> 9) & 7;
    int ks = i >> 12;
    int k = ks * 32 + ((lane >> 4) << 3) + j;
    int c = ct * 16 + (lane & 15);
    float v = (k < D) ? Wl[c * D + k] : Wr[c * D + (k - D)];
    Wpk[i] = f2bf(v);
}

#define PACK_BLOCKS 320   // 81920/256
#define CONV_BLOCKS 3125  // NN*16/256

__global__ __launch_bounds__(256) void prep(
    const float* __restrict__ Wl0, const float* __restrict__ Wr0,
    const float* __restrict__ Wl1, const float* __restrict__ Wr1,
    const float* __restrict__ Wl2, const float* __restrict__ Wr2,
    unsigned short* __restrict__ Wpk0, unsigned short* __restrict__ Wpk1,
    unsigned short* __restrict__ Wpk2,
    const float* __restrict__ x, unsigned short* __restrict__ A0,
    int* __restrict__ meta) {
    const int S0 = 2 * DIN * HD;   // 16384
    const int S12 = 2 * HD * HD;   // 32768
    int b = blockIdx.x;
    int t = threadIdx.x;
    if (b < PACK_BLOCKS) {
        int i = b * 256 + t;
        if (i < S0) { pack_one(Wl0, Wr0, DIN, Wpk0, i); return; }
        int j = i - S0;
        if (j < S12) { pack_one(Wl1, Wr1, HD, Wpk1, j); return; }
        int m = j - S12;
        if (m < S12) pack_one(Wl2, Wr2, HD, Wpk2, m);
        return;
    }
    if (b < PACK_BLOCKS + CONV_BLOCKS) {
        // x f32 [NN][64] -> bf16 into A0[:, 64:128] (row stride 128 shorts)
        int i = (b - PACK_BLOCKS) * 256 + t;   // < NN*16
        int row = i >> 4, c4 = i & 15;
        float4 v = ((const float4*)(x + (size_t)row * DIN))[c4];
        us4 o = {f2bf(v.x), f2bf(v.y), f2bf(v.z), f2bf(v.w)};
        *(us4*)(A0 + (size_t)row * 128 + 64 + c4 * 4) = o;
        return;
    }
    // last block: zero meta (bcnt[256] + bfill[256]) — 256 threads cover 512 ints
    meta[t] = 0;
    meta[t + 256] = 0;
}

// ---------------- gather-mean layer 0: half-wave per node, 4-deep pipeline ----------------
// 8 nodes/block; 32 lanes/node = 4 edge-groups x 8 ch-lanes (us8 = 64ch).

__global__ __launch_bounds__(256) void gather_mean_x(
    const int* __restrict__ rowptr, const int* __restrict__ csr_src,
    const float* __restrict__ invcnt, unsigned short* __restrict__ A0) {
    int tid = threadIdx.x;
    int n = blockIdx.x * 8 + (tid >> 5);
    int c8 = tid & 7;
    int eg = (tid >> 3) & 3;
    int beg = rowptr[n], end = rowptr[n + 1];
    float acc[8] = {};
    const unsigned short* hb = A0 + 64 + (size_t)c8 * 8;
    int e = beg + eg;
    for (; e + 12 < end; e += 16) {  // 4-deep load pipeline
        int i0 = csr_src[e], i1 = csr_src[e + 4], i2 = csr_src[e + 8], i3 = csr_src[e + 12];
        us8 v0 = *(const us8*)(hb + (size_t)i0 * 128);
        us8 v1 = *(const us8*)(hb + (size_t)i1 * 128);
        us8 v2 = *(const us8*)(hb + (size_t)i2 * 128);
        us8 v3 = *(const us8*)(hb + (size_t)i3 * 128);
#pragma unroll
        for (int j = 0; j < 8; ++j)
            acc[j] += (bf2f(v0[j]) + bf2f(v1[j])) + (bf2f(v2[j]) + bf2f(v3[j]));
    }
    for (; e < end; e += 4) {
        us8 v0 = *(const us8*)(hb + (size_t)csr_src[e] * 128);
#pragma unroll
        for (int j = 0; j < 8; ++j) acc[j] += bf2f(v0[j]);
    }
#pragma unroll
    for (int j = 0; j < 8; ++j) {
        acc[j] += __shfl_xor(acc[j], 8, 64);
        acc[j] += __shfl_xor(acc[j], 16, 64);
    }
    if (eg == 0) {
        float ic = invcnt[n];
        us8 o;
#pragma unroll
        for (int j = 0; j < 8; ++j) o[j] = f2bf(acc[j] * ic);
        *(us8*)(A0 + (size_t)n * 128 + c8 * 8) = o;
    }
}

// ---------------- gather-mean layers 1,2: wave per node, 4-deep pipeline ----------------
// 4 nodes/block; 64 lanes/node = 4 edge-groups x 16 ch-lanes (us8 = 128ch).

__global__ __launch_bounds__(256) void gather_mean_h(
    const unsigned short* __restrict__ A12, const int* __restrict__ rowptr,
    const int* __restrict__ csr_src, const float* __restrict__ invcnt,
    unsigned short* __restrict__ Am) {
    int tid = threadIdx.x;
    int n = blockIdx.x * 4 + (tid >> 6);
    int lane = tid & 63;
    int c8 = lane & 15;
    int eg = lane >> 4;
    int beg = rowptr[n], end = rowptr[n + 1];
    float acc[8] = {};
    const unsigned short* hb = A12 + 128 + (size_t)c8 * 8;
    int e = beg + eg;
    for (; e + 12 < end; e += 16) {  // 4-deep load pipeline
        int i0 = csr_src[e], i1 = csr_src[e + 4], i2 = csr_src[e + 8], i3 = csr_src[e + 12];
        us8 v0 = *(const us8*)(hb + (size_t)i0 * 256);
        us8 v1 = *(const us8*)(hb + (size_t)i1 * 256);
        us8 v2 = *(const us8*)(hb + (size_t)i2 * 256);
        us8 v3 = *(const us8*)(hb + (size_t)i3 * 256);
#pragma unroll
        for (int j = 0; j < 8; ++j)
            acc[j] += (bf2f(v0[j]) + bf2f(v1[j])) + (bf2f(v2[j]) + bf2f(v3[j]));
    }
    for (; e < end; e += 4) {
        us8 v0 = *(const us8*)(hb + (size_t)csr_src[e] * 256);
#pragma unroll
        for (int j = 0; j < 8; ++j) acc[j] += bf2f(v0[j]);
    }
#pragma unroll
    for (int j = 0; j < 8; ++j) {
        acc[j] += __shfl_xor(acc[j], 16, 64);
        acc[j] += __shfl_xor(acc[j], 32, 64);
    }
    if (eg == 0) {
        float ic = invcnt[n];
        us8 o;
#pragma unroll
        for (int j = 0; j < 8; ++j) o[j] = f2bf(acc[j] * ic);
        *(us8*)(Am + (size_t)n * 256 + c8 * 8) = o;
    }
}

// ---------------- fused MFMA GEMM + bias + L2 norm + (ReLU) ----------------

template <int K, bool RELU, bool F32OUT, bool BF16H>
__global__ __launch_bounds__(256) void linear_mfma(
    const unsigned short* __restrict__ A, const unsigned short* __restrict__ Wpk,
    const float* __restrict__ bias, float* __restrict__ outF,
    unsigned short* __restrict__ Hn /* h-part base (stride 256) */) {
    constexpr int NK = K / 32;
    __shared__ float rsum[2][32];
    int tid = threadIdx.x;
    int lane = tid & 63, w = tid >> 6;
    int rg = w >> 1, cg = w & 1;
    int r0 = blockIdx.x * 32 + rg * 16;
    int row_l = lane & 15, kb = lane >> 4;

    const unsigned short* Arow = A + (size_t)(r0 + row_l) * K + kb * 8;
    const unsigned short* Wp = Wpk + ((size_t)(cg * 4) * 64 + lane) * 8;

    f32x4 acc[4] = {{0.f, 0.f, 0.f, 0.f}, {0.f, 0.f, 0.f, 0.f},
                    {0.f, 0.f, 0.f, 0.f}, {0.f, 0.f, 0.f, 0.f}};
#pragma unroll
    for (int ks = 0; ks < NK; ++ks) {
        short8 a = *(const short8*)(Arow + ks * 32);
#pragma unroll
        for (int t = 0; t < 4; ++t) {
            short8 b = *(const short8*)(Wp + ((size_t)ks * 8 + t) * 64 * 8);
            acc[t] = __builtin_amdgcn_mfma_f32_16x16x32_bf16(a, b, acc[t], 0, 0, 0);
        }
    }

    float sq[4] = {0.f, 0.f, 0.f, 0.f};
#pragma unroll
    for (int t = 0; t < 4; ++t) {
        float bv = bias[cg * 64 + t * 16 + row_l];
#pragma unroll
        for (int r = 0; r < 4; ++r) {
            acc[t][r] += bv;
            sq[r] = fmaf(acc[t][r], acc[t][r], sq[r]);
        }
    }
#pragma unroll
    for (int off = 1; off < 16; off <<= 1)
#pragma unroll
        for (int r = 0; r < 4; ++r) sq[r] += __shfl_xor(sq[r], off, 64);

    if (row_l == 0) {
#pragma unroll
        for (int r = 0; r < 4; ++r) rsum[cg][rg * 16 + kb * 4 + r] = sq[r];
    }
    __syncthreads();  // also orders all A reads before the BF16H in-place writes

    int rbase = rg * 16 + kb * 4;
#pragma unroll
    for (int r = 0; r < 4; ++r) {
        int row = r0 + kb * 4 + r;
        if (row >= NN) continue;
        float n2 = rsum[0][rbase + r] + rsum[1][rbase + r];
        float inv = 1.0f / fmaxf(sqrtf(n2), 1e-12f);
#pragma unroll
        for (int t = 0; t < 4; ++t) {
            float v = acc[t][r] * inv;
            if (RELU) v = fmaxf(v, 0.f);
            int c = cg * 64 + t * 16 + row_l;
            if (F32OUT) outF[(size_t)row * HD + c] = v;
            if (BF16H) Hn[(size_t)row * 256 + c] = f2bf(v);
        }
    }
}

// ---------------- launch ----------------

static inline size_t align256(size_t x) { return (x + 255) & ~(size_t)255; }

extern "C" void kernel_launch(void* const* d_in, const int* in_sizes, int n_in,
                              void* d_out, int out_size, void* d_ws, size_t ws_size,
                              hipStream_t stream) {
    const float* x   = (const float*)d_in[0];
    const int*   ei  = (const int*)d_in[1];
    const float* Wl0 = (const float*)d_in[2];
    const float* bl0 = (const float*)d_in[3];
    const float* Wr0 = (const float*)d_in[4];
    const float* Wl1 = (const float*)d_in[5];
    const float* bl1 = (const float*)d_in[6];
    const float* Wr1 = (const float*)d_in[7];
    const float* Wl2 = (const float*)d_in[8];
    const float* bl2 = (const float*)d_in[9];
    const float* Wr2 = (const float*)d_in[10];

    const int* src = ei;
    const int* dst = ei + NE;

    // workspace carve-up
    char* p = (char*)d_ws;
    size_t off = 0;
    int* meta = (int*)(p + off);            off = align256(off + 512 * 4);
    int* bbase = (int*)(p + off);           off = align256(off + 256 * 4);
    int* rowptr = (int*)(p + off);          off = align256(off + (size_t)(NN + 1) * 4);
    int* csr_src = (int*)(p + off);         off = align256(off + (size_t)NE * 4);
    float* invcnt = (float*)(p + off);      off = align256(off + (size_t)NN * 4);
    int* pairs = (int*)(p + off);           off = align256(off + (size_t)NE * 4);
    unsigned short* A0 = (unsigned short*)(p + off);   off = align256(off + (size_t)NNP * 128 * 2);
    unsigned short* A12 = (unsigned short*)(p + off);  off = align256(off + (size_t)NNP * 256 * 2);
    unsigned short* Wpk0 = (unsigned short*)(p + off); off = align256(off + (size_t)2 * DIN * HD * 2);
    unsigned short* Wpk1 = (unsigned short*)(p + off); off = align256(off + (size_t)2 * HD * HD * 2);
    unsigned short* Wpk2 = (unsigned short*)(p + off); off = align256(off + (size_t)2 * HD * HD * 2);
    (void)ws_size; (void)n_in; (void)in_sizes; (void)out_size;

    int* bcnt = meta;
    int* bfill = meta + 256;
    float* out = (float*)d_out;

    // prep first (packs weights, converts x, zeroes meta — all independent of CSR)
    prep<<<PACK_BLOCKS + CONV_BLOCKS + 1, 256, 0, stream>>>(
        Wl0, Wr0, Wl1, Wr1, Wl2, Wr2, Wpk0, Wpk1, Wpk2, x, A0, meta);

    // CSR build: two-level LDS counting sort (packed pairs, no binary search)
    bucket_count<<<SB, 256, 0, stream>>>(dst, bcnt);
    bucket_scan<<<1, 256, 0, stream>>>(bcnt, bbase, rowptr);
    bucket_scatter<<<SB, 256, 0, stream>>>(src, dst, bbase, bfill, pairs);
    build_csr<<<NBUK, 256, 0, stream>>>(pairs, bbase, rowptr, invcnt, csr_src);

    const int LG = NNP / 32;     // 1563
    const int GX = NN / 8;       // 6250
    const int GH = NN / 4;       // 12500

    // layer 0: gather bf16 x rows -> A0 mean part; GEMM K=128 -> h0 bf16 into A12[:,128:256]
    gather_mean_x<<<GX, 256, 0, stream>>>(rowptr, csr_src, invcnt, A0);
    linear_mfma<2 * DIN, true, false, true><<<LG, 256, 0, stream>>>(
        A0, Wpk0, bl0, nullptr, A12 + 128);

    // layer 1: gather h0 -> A12 mean part; GEMM K=256 -> h1 bf16 (row-exclusive in-place)
    gather_mean_h<<<GH, 256, 0, stream>>>(A12, rowptr, csr_src, invcnt, A12);
    linear_mfma<2 * HD, true, false, true><<<LG, 256, 0, stream>>>(
        A12, Wpk1, bl1, nullptr, A12 + 128);

    // layer 2: gather h1 -> A12 mean part; GEMM K=256 -> f32 d_out
    gather_mean_h<<<GH, 256, 0, stream>>>(A12, rowptr, csr_src, invcnt, A12);
    linear_mfma<2 * HD, false, true, false><<<LG, 256, 0, stream>>>(
        A12, Wpk2, bl2, out, nullptr);
}